// Round 15
// baseline (158.668 us; speedup 1.0000x reference)
//
#include <hip/hip_runtime.h>
#include <hip/hip_bf16.h>

typedef __bf16 bf16x8 __attribute__((ext_vector_type(8)));
typedef __bf16 bf16x2 __attribute__((ext_vector_type(2)));
typedef float f32x4 __attribute__((ext_vector_type(4)));

#define LN2f 0.6931471805599453f
#define CEf  2.0402785445f   // log2(e)*sqrt(2): exp(-dist) = 2^(-CE*sqrt(sq_dist/2))
// Schraudolph exp2 bit-trick: exp2(-z) ~= as_float((int)(B - z*2^23)), CE folded in.
#define EXPA (-CEf * 8388608.0f)
#define EXPB ((127.0f - 0.0437f) * 8388608.0f)

typedef __attribute__((address_space(3))) unsigned int lds_u32;
typedef __attribute__((address_space(1))) unsigned int glb_u32;

__device__ __forceinline__ void gload16(const void* g, void* l) {
    __builtin_amdgcn_global_load_lds((const glb_u32*)g, (lds_u32*)l, 16, 0, 0);
}

// Kernel 1: prototypes f32 -> bf16 in MFMA B-fragment order + ysqn = -0.5*||y||^2.
// Element e of class c, dim d (d = kk*32 + lg*8 + e) -> bf16 offset
// ((c>>4)*4 + kk)*64*8 + (lg*16 + (c&15))*8 + e.  Tile ct occupies 4096 B.
__global__ void dce_prep(const float* __restrict__ protos,
                         unsigned short* __restrict__ bpf,
                         float* __restrict__ ysqn) {
    int c = blockIdx.x;
    int lane = threadIdx.x;  // dims 2*lane, 2*lane+1
    float2 f = ((const float2*)(protos))[c * 64 + lane];
    int d0 = lane * 2;
    int kk = d0 >> 5, sub = d0 & 31, lg = sub >> 3, e = sub & 7;
    size_t o = (((size_t)((c >> 4) * 4 + kk) * 64) + lg * 16 + (c & 15)) * 8 + e;
    bf16x2 h;
    h.x = (__bf16)f.x;
    h.y = (__bf16)f.y;
    *(bf16x2*)(bpf + o) = h;
    float xs = f.x * f.x + f.y * f.y;
#pragma unroll
    for (int d = 1; d < 64; d <<= 1) xs += __shfl_xor(xs, d);
    if (lane == 0) ysqn[c] = -0.5f * xs;
}

// Kernel 2: fused distance-softmax-NLL. 1024 blocks x 512 threads (8 waves x
// 32 rows). B staged in 32 KB chunks (8 class-tiles) via global_load_lds,
// double-buffered (69 KB LDS -> 2 blocks/CU = 16 waves/CU, the register cap
// anyway); ONE barrier per chunk (8 total), stage for chunk n+1 issues at the
// top of chunk n (~1600 issue-cyc cover). Waves sweep the chunk's 8 tiles at
// staggered offsets (decorrelates trans bursts / LDS reads). Feats A-frag
// loads are non-temporal (last touch; keeps B + label-lines cached).
//   acc_init = -(||x||^2+||y||^2)/2, acc_final = -sq_dist/2,
//   exp(-dist) ~= as_float((int)(EXPB + EXPA*sqrt(-acc)))   (Schraudolph)
//   nll = dist_label + ln2*log2( sum_c exp(-dist_c) )       (softmax max == 0)
__global__ __launch_bounds__(512, 4) void dce_main(
    const float* __restrict__ feats,
    const float* __restrict__ protos,
    const unsigned short* __restrict__ bpf,
    const float* __restrict__ ysqn,
    const int* __restrict__ labels,
    float* __restrict__ partials, int C) {
    const int tid = threadIdx.x;   // 0..511
    const int lane = tid & 63;
    const int w = tid >> 6;        // 0..7
    const int row0 = blockIdx.x * 256;
    const int rbase = row0 + w * 32;
    const int lr = lane & 15;
    const int lg = lane >> 4;

    __shared__ __align__(16) unsigned char bsm[2 * 32768];
    __shared__ __align__(16) float ysql[1024];
    __shared__ float red[8];

    const char* bpc = (const char*)bpf;
    const int c0 = blockIdx.x & 7;   // chunk rotation across blocks (8 chunks)

#define STAGE(buf, chunkIdx)                                                   \
    {                                                                          \
        const char* src_ = bpc + (size_t)(chunkIdx) * 32768 + tid * 16;        \
        _Pragma("unroll") for (int kt = 0; kt < 4; ++kt)                       \
            gload16(src_ + kt * 8192, (buf) + kt * 8192 + tid * 16);           \
    }

    // ---- Prologue DMA: chunk c0 + ysql (waves 0..3 only, wave-uniform) ----
    STAGE(bsm, c0);
    if (tid < 256) gload16((const char*)ysqn + tid * 16, (char*)ysql + tid * 16);

    // ---- Phase 1: exact f32 label distance, 2 threads per row ----
    const int r1 = row0 + (tid >> 1);
    const int half = tid & 1;
    const int lab = labels[r1];
    const f32x4* fx = (const f32x4*)(feats) + (size_t)r1 * 32 + half * 16;
    const f32x4* px = (const f32x4*)(protos) + (size_t)lab * 32 + half * 16;
    float xx = 0.f, yy = 0.f, xy = 0.f;
#pragma unroll
    for (int i = 0; i < 16; ++i) {
        f32x4 f = fx[i];   // cached: same lines re-read by A-fragment loads
        f32x4 p = px[i];
        xx = fmaf(f[0], f[0], fmaf(f[1], f[1], fmaf(f[2], f[2], fmaf(f[3], f[3], xx))));
        yy = fmaf(p[0], p[0], fmaf(p[1], p[1], fmaf(p[2], p[2], fmaf(p[3], p[3], yy))));
        xy = fmaf(f[0], p[0], fmaf(f[1], p[1], fmaf(f[2], p[2], fmaf(f[3], p[3], xy))));
    }
    xx += __shfl_xor(xx, 1);
    yy += __shfl_xor(yy, 1);
    xy += __shfl_xor(xy, 1);
    const float ld = __builtin_amdgcn_sqrtf(fmaxf(fmaf(-2.f, xy, xx + yy), 0.f));

    // ---- A fragments: 2 M-frags x 4 k-slices (non-temporal: last touch) ----
    bf16x8 a[2][4];
    const f32x4* f4 = (const f32x4*)feats;
#pragma unroll
    for (int m = 0; m < 2; ++m) {
        size_t r = (size_t)(rbase + m * 16 + lr);
#pragma unroll
        for (int kk = 0; kk < 4; ++kk) {
            size_t idx = r * 32 + kk * 8 + lg * 2;
            f32x4 lo = __builtin_nontemporal_load(f4 + idx);
            f32x4 hi = __builtin_nontemporal_load(f4 + idx + 1);
            bf16x8 v;
            v[0] = (__bf16)lo[0]; v[1] = (__bf16)lo[1]; v[2] = (__bf16)lo[2]; v[3] = (__bf16)lo[3];
            v[4] = (__bf16)hi[0]; v[5] = (__bf16)hi[1]; v[6] = (__bf16)hi[2]; v[7] = (__bf16)hi[3];
            a[m][kk] = v;
        }
    }

    // -0.5*||x||^2 in C/D layout: element (m,reg) covers row m*16+lg*4+reg,
    // whose exact xx lives at wave-lane 2*(that row-in-wave).
    float pre[2][4];
#pragma unroll
    for (int m = 0; m < 2; ++m)
#pragma unroll
        for (int reg = 0; reg < 4; ++reg)
            pre[m][reg] = -0.5f * __shfl(xx, 2 * (m * 16 + lg * 4 + reg));

    float lacc[2][4];
#pragma unroll
    for (int m = 0; m < 2; ++m)
#pragma unroll
        for (int reg = 0; reg < 4; ++reg) lacc[m][reg] = 0.f;

#define TILE(buf, kt, tt)                                                       \
    {                                                                           \
        const bf16x8* bl_ = (const bf16x8*)((buf) + (size_t)(kt) * 4096);       \
        bf16x8 b0 = bl_[lane];                                                  \
        bf16x8 b1 = bl_[64 + lane];                                             \
        bf16x8 b2 = bl_[128 + lane];                                            \
        bf16x8 b3 = bl_[192 + lane];                                            \
        const float yq_ = ysql[(tt) * 16 + lr];                                 \
        _Pragma("unroll") for (int m = 0; m < 2; ++m) {                         \
            f32x4 acc;                                                          \
            acc[0] = pre[m][0] + yq_;                                           \
            acc[1] = pre[m][1] + yq_;                                           \
            acc[2] = pre[m][2] + yq_;                                           \
            acc[3] = pre[m][3] + yq_;                                           \
            acc = __builtin_amdgcn_mfma_f32_16x16x32_bf16(a[m][0], b0, acc, 0, 0, 0); \
            acc = __builtin_amdgcn_mfma_f32_16x16x32_bf16(a[m][1], b1, acc, 0, 0, 0); \
            acc = __builtin_amdgcn_mfma_f32_16x16x32_bf16(a[m][2], b2, acc, 0, 0, 0); \
            acc = __builtin_amdgcn_mfma_f32_16x16x32_bf16(a[m][3], b3, acc, 0, 0, 0); \
            _Pragma("unroll") for (int reg = 0; reg < 4; ++reg) {               \
                float s_ = __builtin_amdgcn_sqrtf(-acc[reg]);  /* sqrt(sqd/2) */\
                int i_ = (int)fmaf(s_, EXPA, EXPB);            /* Schraudolph */\
                lacc[m][reg] += __int_as_float(i_);                             \
            }                                                                   \
        }                                                                       \
    }

    // ---- Prologue drain: chunk c0 + ysql resident ----
    asm volatile("s_waitcnt vmcnt(0)" ::: "memory");
    __builtin_amdgcn_s_barrier();

    // ---- Chunk loop: 8 chunks x 8 tiles, double-buffered, 1 barrier/chunk --
#pragma unroll 1
    for (int ch = 0; ch < 8; ++ch) {
        unsigned char* curb = bsm + (size_t)(ch & 1) * 32768;
        const int ci = (c0 + ch) & 7;
        if (ch < 7) {
            unsigned char* nb = bsm + (size_t)((ch + 1) & 1) * 32768;
            STAGE(nb, (ci + 1) & 7);
        }
        // Wave-staggered sweep of the chunk's 8 tiles.
#pragma unroll
        for (int i = 0; i < 8; ++i) {
            const int kt = (w + i) & 7;
            TILE(curb, kt, ci * 8 + kt);
        }
        // Stage DMA had a full chunk (~8 tiles) of cover -> drain ~free.
        asm volatile("s_waitcnt vmcnt(0)" ::: "memory");
        __builtin_amdgcn_s_barrier();
    }

#undef STAGE
#undef TILE

    // ---- Reduce over 16 column-lanes per row, add exact label distance ----
    float ssum = 0.f;
#pragma unroll
    for (int m = 0; m < 2; ++m)
#pragma unroll
        for (int reg = 0; reg < 4; ++reg) {
            float l = lacc[m][reg];
            l += __shfl_xor(l, 1);
            l += __shfl_xor(l, 2);
            l += __shfl_xor(l, 4);
            l += __shfl_xor(l, 8);
            float ldv = __shfl(ld, 2 * (m * 16 + lg * 4 + reg));
            if (lr == 0) ssum += ldv + LN2f * __builtin_amdgcn_logf(l);
        }
    ssum += __shfl_xor(ssum, 16);
    ssum += __shfl_xor(ssum, 32);

    if (lane == 0) red[w] = ssum;
    __syncthreads();
    if (tid == 0) {
        float s = 0.f;
#pragma unroll
        for (int i = 0; i < 8; ++i) s += red[i];
        partials[blockIdx.x] = s;
    }
}

// Kernel 3: deterministic reduction of per-block partials -> mean.
__global__ void dce_finish(const float* __restrict__ partials,
                           float* __restrict__ out, int nblocks, float invN) {
    int tid = threadIdx.x;  // 256
    float s = 0.f;
    for (int i = tid; i < nblocks; i += 256) s += partials[i];
#pragma unroll
    for (int d = 1; d < 64; d <<= 1) s += __shfl_xor(s, d);
    __shared__ float red[4];
    if ((tid & 63) == 0) red[tid >> 6] = s;
    __syncthreads();
    if (tid == 0) out[0] = (red[0] + red[1] + red[2] + red[3]) * invN;
}

extern "C" void kernel_launch(void* const* d_in, const int* in_sizes, int n_in,
                              void* d_out, int out_size, void* d_ws, size_t ws_size,
                              hipStream_t stream) {
    const float* feats = (const float*)d_in[0];
    const float* protos = (const float*)d_in[1];
    const int* labels = (const int*)d_in[2];
    const int N = in_sizes[2];          // 262144
    const int C = in_sizes[1] / 128;    // 1024
    float* out = (float*)d_out;

    // Workspace: [bpf: C*128*2B][ysqn: C*4B][partials: N/256*4B]
    unsigned short* bpf = (unsigned short*)d_ws;
    float* ysqn = (float*)((char*)d_ws + (size_t)C * 128 * 2);
    float* partials = ysqn + C;
    const int nblocks = N / 256;   // 1024 blocks of 512 threads

    dce_prep<<<C, 64, 0, stream>>>(protos, bpf, ysqn);
    dce_main<<<nblocks, 512, 0, stream>>>(feats, protos, bpf, ysqn, labels, partials, C);
    dce_finish<<<1, 256, 0, stream>>>(partials, out, nblocks, 1.0f / (float)N);
}

// Round 16
// 128.369 us; speedup vs baseline: 1.2360x; 1.2360x over previous
//
#include <hip/hip_runtime.h>
#include <hip/hip_bf16.h>

typedef __bf16 bf16x8 __attribute__((ext_vector_type(8)));
typedef __bf16 bf16x2 __attribute__((ext_vector_type(2)));
typedef float f32x4 __attribute__((ext_vector_type(4)));
typedef float f32x16 __attribute__((ext_vector_type(16)));

#define LN2f 0.6931471805599453f
#define CEf  2.0402785445f   // log2(e)*sqrt(2): exp(-dist) = 2^(-CE*sqrt(sq_dist/2))
// Schraudolph exp2 bit-trick: exp2(-z) ~= as_float((int)(B - z*2^23)), CE folded in.
#define EXPA (-CEf * 8388608.0f)
#define EXPB ((127.0f - 0.0437f) * 8388608.0f)

typedef __attribute__((address_space(3))) unsigned int lds_u32;
typedef __attribute__((address_space(1))) unsigned int glb_u32;

__device__ __forceinline__ void gload16(const void* g, void* l) {
    __builtin_amdgcn_global_load_lds((const glb_u32*)g, (lds_u32*)l, 16, 0, 0);
}

// Kernel 1: prototypes f32 -> bf16 in 32x32x16-MFMA B-fragment order +
// ysqn = -0.5*||y||^2.  For class c, dim d: kk = d>>4 (0..7), g = (d>>3)&1,
// e = d&7 -> bf16x8 unit (c>>5)*512 + (kk*2+g)*32 + (c&31), element e.
// One 32-class tile = 512 units = 8 KB; chunk = 2 tiles = 16 KB.
__global__ void dce_prep(const float* __restrict__ protos,
                         unsigned short* __restrict__ bpf,
                         float* __restrict__ ysqn) {
    int c = blockIdx.x;
    int lane = threadIdx.x;  // dims 2*lane, 2*lane+1
    float2 f = ((const float2*)(protos))[c * 64 + lane];
    int d0 = lane * 2;
    int kk = d0 >> 4;          // 0..7
    int g = (d0 >> 3) & 1;
    int e = d0 & 7;            // even; covers e, e+1
    size_t unit = (size_t)(c >> 5) * 512 + (size_t)(kk * 2 + g) * 32 + (c & 31);
    bf16x2 h;
    h.x = (__bf16)f.x;
    h.y = (__bf16)f.y;
    *(bf16x2*)(bpf + unit * 8 + e) = h;
    float xs = f.x * f.x + f.y * f.y;
#pragma unroll
    for (int d = 1; d < 64; d <<= 1) xs += __shfl_xor(xs, d);
    if (lane == 0) ysqn[c] = -0.5f * xs;
}

// Kernel 2: fused distance-softmax-NLL, 32x32x16 MFMA.  2048 blocks x 256
// threads; wave owns 32 rows (ONE 32-row M-frag).  B staged in 16 KB chunks
// (two 32-class tiles) via global_load_lds, double-buffered, 1 barrier/chunk
// (R11 chassis).  Per tile: 8 chained mfma_f32_32x32x16_bf16 (K=128), then 16
// INDEPENDENT epilogue lanes-elements (4x the trans ILP of the 16x16 shape).
//   acc_init = -(||x||^2+||y||^2)/2, acc_final = -sq_dist/2,
//   exp(-dist) ~= as_float((int)(EXPB + EXPA*sqrt(-acc)))   (Schraudolph)
//   nll = dist_label + ln2*log2( sum_c exp(-dist_c) )       (softmax max == 0)
// C/D layout (verified m74/m101): col = lane&31, row = (reg&3)+8*(reg>>2)+4*(lane>>5).
__global__ __launch_bounds__(256, 4) void dce_main(
    const float* __restrict__ feats,
    const float* __restrict__ protos,
    const unsigned short* __restrict__ bpf,
    const float* __restrict__ ysqn,
    const int* __restrict__ labels,
    float* __restrict__ partials, int C) {
    const int tid = threadIdx.x;   // 0..255
    const int lane = tid & 63;
    const int w = tid >> 6;        // 0..3
    const int row0 = blockIdx.x * 128;
    const int rbase = row0 + w * 32;
    const int col = lane & 31;
    const int g = lane >> 5;       // k-group (A/B) and +4-row select (C/D)

    __shared__ __align__(16) unsigned char bsm[2 * 16384];
    __shared__ __align__(16) float ysql[1024];
    __shared__ float red[4];

    const char* bpc = (const char*)bpf;
    const int c0 = (blockIdx.x >> 3) & 15;   // chunk rotation across blocks

#define STAGE(buf, chunkIdx)                                                   \
    {                                                                          \
        const char* src_ = bpc + (size_t)(chunkIdx) * 16384 + tid * 16;        \
        _Pragma("unroll") for (int kt = 0; kt < 4; ++kt)                       \
            gload16(src_ + kt * 4096, (buf) + kt * 4096 + tid * 16);           \
    }

    // ---- Prologue DMA: ysql + chunk c0 ----
    gload16((const char*)ysqn + tid * 16, (char*)ysql + tid * 16);
    STAGE(bsm, c0);

    // ---- Phase 1: exact f32 label distance, 2 threads per row ----
    const int r1 = row0 + (tid >> 1);
    const int half = tid & 1;
    const int lab = labels[r1];
    const f32x4* fx = (const f32x4*)(feats) + (size_t)r1 * 32 + half * 16;
    const f32x4* px = (const f32x4*)(protos) + (size_t)lab * 32 + half * 16;
    float xx = 0.f, yy = 0.f, xy = 0.f;
#pragma unroll
    for (int i = 0; i < 16; ++i) {
        f32x4 f = fx[i];   // cached: same lines re-read by A-fragment loads
        f32x4 p = px[i];
        xx = fmaf(f[0], f[0], fmaf(f[1], f[1], fmaf(f[2], f[2], fmaf(f[3], f[3], xx))));
        yy = fmaf(p[0], p[0], fmaf(p[1], p[1], fmaf(p[2], p[2], fmaf(p[3], p[3], yy))));
        xy = fmaf(f[0], p[0], fmaf(f[1], p[1], fmaf(f[2], p[2], fmaf(f[3], p[3], xy))));
    }
    xx += __shfl_xor(xx, 1);
    yy += __shfl_xor(yy, 1);
    xy += __shfl_xor(xy, 1);
    const float ld = __builtin_amdgcn_sqrtf(fmaxf(fmaf(-2.f, xy, xx + yy), 0.f));

    // ---- A fragments: 8 k-slices of the wave's 32 rows (non-temporal) ----
    // a[kk] element e  <->  feats[rbase+col][kk*16 + g*8 + e]
    bf16x8 a[8];
    {
        const f32x4* f4 = (const f32x4*)feats;
        size_t r = (size_t)(rbase + col);
#pragma unroll
        for (int kk = 0; kk < 8; ++kk) {
            size_t idx = r * 32 + kk * 4 + g * 2;
            f32x4 lo = __builtin_nontemporal_load(f4 + idx);
            f32x4 hi = __builtin_nontemporal_load(f4 + idx + 1);
            bf16x8 v;
            v[0] = (__bf16)lo[0]; v[1] = (__bf16)lo[1]; v[2] = (__bf16)lo[2]; v[3] = (__bf16)lo[3];
            v[4] = (__bf16)hi[0]; v[5] = (__bf16)hi[1]; v[6] = (__bf16)hi[2]; v[7] = (__bf16)hi[3];
            a[kk] = v;
        }
    }

    // -0.5*||x||^2 in C/D layout: element reg covers row (reg&3)+8*(reg>>2)+4*g,
    // whose exact xx lives at wave-lane 2*(that row-in-wave).
    float pre[16];
#pragma unroll
    for (int reg = 0; reg < 16; ++reg)
        pre[reg] = -0.5f * __shfl(xx, 2 * ((reg & 3) + 8 * (reg >> 2) + 4 * g));

    float lacc[16];
#pragma unroll
    for (int reg = 0; reg < 16; ++reg) lacc[reg] = 0.f;

#define TILE(buf, kt, tt)                                                       \
    {                                                                           \
        const bf16x8* bl_ = (const bf16x8*)((buf) + (size_t)(kt) * 8192);       \
        const float yq_ = ysql[(tt) * 32 + col];                                \
        f32x16 acc;                                                             \
        _Pragma("unroll") for (int reg = 0; reg < 16; ++reg)                    \
            acc[reg] = pre[reg] + yq_;                                          \
        _Pragma("unroll") for (int kk = 0; kk < 8; ++kk) {                      \
            bf16x8 b_ = bl_[(kk * 2 + g) * 32 + col];                           \
            acc = __builtin_amdgcn_mfma_f32_32x32x16_bf16(a[kk], b_, acc, 0, 0, 0); \
        }                                                                       \
        _Pragma("unroll") for (int reg = 0; reg < 16; ++reg) {                  \
            float s_ = __builtin_amdgcn_sqrtf(-acc[reg]);  /* sqrt(sqd/2) */    \
            int i_ = (int)fmaf(s_, EXPA, EXPB);            /* Schraudolph */    \
            lacc[reg] += __int_as_float(i_);                                    \
        }                                                                       \
    }

    // ---- Chunk loop: 16 chunks x 2 tiles, double-buffered, 1 barrier/chunk --
    __syncthreads();  // ysql + chunk c0 resident
#pragma unroll 2
    for (int ch = 0; ch < 16; ++ch) {
        unsigned char* curb = bsm + (size_t)(ch & 1) * 16384;
        const int ci = (c0 + ch) & 15;
        if (ch + 1 < 16) {
            unsigned char* nxtb = bsm + (size_t)((ch + 1) & 1) * 16384;
            STAGE(nxtb, (ci + 1) & 15);
        }
        TILE(curb, 0, ci * 2);
        TILE(curb, 1, ci * 2 + 1);
        __syncthreads();  // stage had ~2 tiles of cover; also read-fence
    }

#undef STAGE
#undef TILE

    // ---- Reduce over 32 column-lanes per row, add exact label distance ----
    float ssum = 0.f;
#pragma unroll
    for (int reg = 0; reg < 16; ++reg) {
        float l = lacc[reg];
        l += __shfl_xor(l, 1);
        l += __shfl_xor(l, 2);
        l += __shfl_xor(l, 4);
        l += __shfl_xor(l, 8);
        l += __shfl_xor(l, 16);
        const int r_ = (reg & 3) + 8 * (reg >> 2) + 4 * g;
        float ldv = __shfl(ld, 2 * r_);
        if (col == 0) ssum += ldv + LN2f * __builtin_amdgcn_logf(l);
    }
    ssum += __shfl_xor(ssum, 32);   // combine the two half-wave row groups

    if (lane == 0) red[w] = ssum;
    __syncthreads();
    if (tid == 0) partials[blockIdx.x] = red[0] + red[1] + red[2] + red[3];
}

// Kernel 3: deterministic reduction of per-block partials -> mean.
__global__ void dce_finish(const float* __restrict__ partials,
                           float* __restrict__ out, int nblocks, float invN) {
    int tid = threadIdx.x;  // 256
    float s = 0.f;
    for (int i = tid; i < nblocks; i += 256) s += partials[i];
#pragma unroll
    for (int d = 1; d < 64; d <<= 1) s += __shfl_xor(s, d);
    __shared__ float red[4];
    if ((tid & 63) == 0) red[tid >> 6] = s;
    __syncthreads();
    if (tid == 0) out[0] = (red[0] + red[1] + red[2] + red[3]) * invN;
}

extern "C" void kernel_launch(void* const* d_in, const int* in_sizes, int n_in,
                              void* d_out, int out_size, void* d_ws, size_t ws_size,
                              hipStream_t stream) {
    const float* feats = (const float*)d_in[0];
    const float* protos = (const float*)d_in[1];
    const int* labels = (const int*)d_in[2];
    const int N = in_sizes[2];          // 262144
    const int C = in_sizes[1] / 128;    // 1024
    float* out = (float*)d_out;

    // Workspace: [bpf: C*128*2B][ysqn: C*4B][partials: N/128*4B]
    unsigned short* bpf = (unsigned short*)d_ws;
    float* ysqn = (float*)((char*)d_ws + (size_t)C * 128 * 2);
    float* partials = ysqn + C;
    const int nblocks = N / 128;   // 2048 blocks of 256 threads

    dce_prep<<<C, 64, 0, stream>>>(protos, bpf, ysqn);
    dce_main<<<nblocks, 256, 0, stream>>>(feats, protos, bpf, ysqn, labels, partials, C);
    dce_finish<<<1, 256, 0, stream>>>(partials, out, nblocks, 1.0f / (float)N);
}

// Round 17
// 122.206 us; speedup vs baseline: 1.2984x; 1.0504x over previous
//
#include <hip/hip_runtime.h>
#include <hip/hip_bf16.h>

typedef __bf16 bf16x8 __attribute__((ext_vector_type(8)));
typedef __bf16 bf16x2 __attribute__((ext_vector_type(2)));
typedef float f32x4 __attribute__((ext_vector_type(4)));
typedef float f32x16 __attribute__((ext_vector_type(16)));

#define LN2f 0.6931471805599453f
#define CEf  2.0402785445f   // log2(e)*sqrt(2): exp(-dist) = 2^(-CE*sqrt(sq_dist/2))
// Schraudolph exp2 bit-trick: exp2(-z) ~= as_float((int)(B - z*2^23)), CE folded in.
#define EXPA (-CEf * 8388608.0f)
#define EXPB ((127.0f - 0.0437f) * 8388608.0f)

typedef __attribute__((address_space(3))) unsigned int lds_u32;
typedef __attribute__((address_space(1))) unsigned int glb_u32;

__device__ __forceinline__ void gload16(const void* g, void* l) {
    __builtin_amdgcn_global_load_lds((const glb_u32*)g, (lds_u32*)l, 16, 0, 0);
}

// Kernel 1: prototypes f32 -> bf16 in 32x32x16-MFMA B-fragment order +
// ysqn = -0.5*||y||^2.  For class c, dim d: kk = d>>4 (0..7), g = (d>>3)&1,
// e = d&7 -> bf16x8 unit (c>>5)*512 + (kk*2+g)*32 + (c&31), element e.
// One 32-class tile = 512 units = 8 KB; chunk = 2 tiles = 16 KB.
__global__ void dce_prep(const float* __restrict__ protos,
                         unsigned short* __restrict__ bpf,
                         float* __restrict__ ysqn) {
    int c = blockIdx.x;
    int lane = threadIdx.x;  // dims 2*lane, 2*lane+1
    float2 f = ((const float2*)(protos))[c * 64 + lane];
    int d0 = lane * 2;
    int kk = d0 >> 4;          // 0..7
    int g = (d0 >> 3) & 1;
    int e = d0 & 7;            // even; covers e, e+1
    size_t unit = (size_t)(c >> 5) * 512 + (size_t)(kk * 2 + g) * 32 + (c & 31);
    bf16x2 h;
    h.x = (__bf16)f.x;
    h.y = (__bf16)f.y;
    *(bf16x2*)(bpf + unit * 8 + e) = h;
    float xs = f.x * f.x + f.y * f.y;
#pragma unroll
    for (int d = 1; d < 64; d <<= 1) xs += __shfl_xor(xs, d);
    if (lane == 0) ysqn[c] = -0.5f * xs;
}

// Kernel 2: fused distance-softmax-NLL, 32x32x16 MFMA (R16 structure).
// 2048 blocks x 256 threads; wave owns 32 rows (one 32-row M-frag). B staged
// in 16 KB chunks (two 32-class tiles) via global_load_lds, double-buffered,
// 1 barrier/chunk. (256,3): the register file limits residency to 3 blocks/CU
// anyway (R16 measured); the (256,4) cap only caused a 6-dword/thread spill
// (12 MB scratch traffic) without buying a 4th block.
//   acc_init = -(||x||^2+||y||^2)/2, acc_final = -sq_dist/2,
//   exp(-dist) ~= as_float((int)(EXPB + EXPA*sqrt(-acc)))   (Schraudolph)
//   nll = dist_label + ln2*log2( sum_c exp(-dist_c) )       (softmax max == 0)
// C/D layout (verified m74/m101): col = lane&31, row = (reg&3)+8*(reg>>2)+4*(lane>>5).
__global__ __launch_bounds__(256, 3) void dce_main(
    const float* __restrict__ feats,
    const float* __restrict__ protos,
    const unsigned short* __restrict__ bpf,
    const float* __restrict__ ysqn,
    const int* __restrict__ labels,
    float* __restrict__ partials, int C) {
    const int tid = threadIdx.x;   // 0..255
    const int lane = tid & 63;
    const int w = tid >> 6;        // 0..3
    const int row0 = blockIdx.x * 128;
    const int rbase = row0 + w * 32;
    const int col = lane & 31;
    const int g = lane >> 5;       // k-group (A/B) and +4-row select (C/D)

    __shared__ __align__(16) unsigned char bsm[2 * 16384];
    __shared__ __align__(16) float ysql[1024];
    __shared__ float red[4];

    const char* bpc = (const char*)bpf;
    const int c0 = (blockIdx.x >> 3) & 15;   // chunk rotation across blocks

#define STAGE(buf, chunkIdx)                                                   \
    {                                                                          \
        const char* src_ = bpc + (size_t)(chunkIdx) * 16384 + tid * 16;        \
        _Pragma("unroll") for (int kt = 0; kt < 4; ++kt)                       \
            gload16(src_ + kt * 4096, (buf) + kt * 4096 + tid * 16);           \
    }

    // ---- Prologue DMA: ysql + chunk c0 ----
    gload16((const char*)ysqn + tid * 16, (char*)ysql + tid * 16);
    STAGE(bsm, c0);

    // ---- Phase 1: exact f32 label distance, 2 threads per row ----
    const int r1 = row0 + (tid >> 1);
    const int half = tid & 1;
    const int lab = labels[r1];
    const f32x4* fx = (const f32x4*)(feats) + (size_t)r1 * 32 + half * 16;
    const f32x4* px = (const f32x4*)(protos) + (size_t)lab * 32 + half * 16;
    float xx = 0.f, yy = 0.f, xy = 0.f;
#pragma unroll
    for (int i = 0; i < 16; ++i) {
        f32x4 f = fx[i];   // cached: same lines re-read by A-fragment loads
        f32x4 p = px[i];
        xx = fmaf(f[0], f[0], fmaf(f[1], f[1], fmaf(f[2], f[2], fmaf(f[3], f[3], xx))));
        yy = fmaf(p[0], p[0], fmaf(p[1], p[1], fmaf(p[2], p[2], fmaf(p[3], p[3], yy))));
        xy = fmaf(f[0], p[0], fmaf(f[1], p[1], fmaf(f[2], p[2], fmaf(f[3], p[3], xy))));
    }
    xx += __shfl_xor(xx, 1);
    yy += __shfl_xor(yy, 1);
    xy += __shfl_xor(xy, 1);
    const float ld = __builtin_amdgcn_sqrtf(fmaxf(fmaf(-2.f, xy, xx + yy), 0.f));

    // ---- A fragments: 8 k-slices of the wave's 32 rows (non-temporal) ----
    // a[kk] element e  <->  feats[rbase+col][kk*16 + g*8 + e]
    bf16x8 a[8];
    {
        const f32x4* f4 = (const f32x4*)feats;
        size_t r = (size_t)(rbase + col);
#pragma unroll
        for (int kk = 0; kk < 8; ++kk) {
            size_t idx = r * 32 + kk * 4 + g * 2;
            f32x4 lo = __builtin_nontemporal_load(f4 + idx);
            f32x4 hi = __builtin_nontemporal_load(f4 + idx + 1);
            bf16x8 v;
            v[0] = (__bf16)lo[0]; v[1] = (__bf16)lo[1]; v[2] = (__bf16)lo[2]; v[3] = (__bf16)lo[3];
            v[4] = (__bf16)hi[0]; v[5] = (__bf16)hi[1]; v[6] = (__bf16)hi[2]; v[7] = (__bf16)hi[3];
            a[kk] = v;
        }
    }

    // -0.5*||x||^2 in C/D layout: element reg covers row (reg&3)+8*(reg>>2)+4*g,
    // whose exact xx lives at wave-lane 2*(that row-in-wave).
    float pre[16];
#pragma unroll
    for (int reg = 0; reg < 16; ++reg)
        pre[reg] = -0.5f * __shfl(xx, 2 * ((reg & 3) + 8 * (reg >> 2) + 4 * g));

    float lacc[16];
#pragma unroll
    for (int reg = 0; reg < 16; ++reg) lacc[reg] = 0.f;

#define TILE(buf, kt, tt)                                                       \
    {                                                                           \
        const bf16x8* bl_ = (const bf16x8*)((buf) + (size_t)(kt) * 8192);       \
        const float yq_ = ysql[(tt) * 32 + col];                                \
        f32x16 acc;                                                             \
        _Pragma("unroll") for (int reg = 0; reg < 16; ++reg)                    \
            acc[reg] = pre[reg] + yq_;                                          \
        _Pragma("unroll") for (int kk = 0; kk < 8; ++kk) {                      \
            bf16x8 b_ = bl_[(kk * 2 + g) * 32 + col];                           \
            acc = __builtin_amdgcn_mfma_f32_32x32x16_bf16(a[kk], b_, acc, 0, 0, 0); \
        }                                                                       \
        _Pragma("unroll") for (int reg = 0; reg < 16; ++reg) {                  \
            float s_ = __builtin_amdgcn_sqrtf(-acc[reg]);  /* sqrt(sqd/2) */    \
            int i_ = (int)fmaf(s_, EXPA, EXPB);            /* Schraudolph */    \
            lacc[reg] += __int_as_float(i_);                                    \
        }                                                                       \
    }

    // ---- Chunk loop: 16 chunks x 2 tiles, double-buffered, 1 barrier/chunk --
    __syncthreads();  // ysql + chunk c0 resident
#pragma unroll 2
    for (int ch = 0; ch < 16; ++ch) {
        unsigned char* curb = bsm + (size_t)(ch & 1) * 16384;
        const int ci = (c0 + ch) & 15;
        if (ch + 1 < 16) {
            unsigned char* nxtb = bsm + (size_t)((ch + 1) & 1) * 16384;
            STAGE(nxtb, (ci + 1) & 15);
        }
        TILE(curb, 0, ci * 2);
        TILE(curb, 1, ci * 2 + 1);
        __syncthreads();  // stage had ~2 tiles of cover; also read-fence
    }

#undef STAGE
#undef TILE

    // ---- Reduce over 32 column-lanes per row, add exact label distance ----
    float ssum = 0.f;
#pragma unroll
    for (int reg = 0; reg < 16; ++reg) {
        float l = lacc[reg];
        l += __shfl_xor(l, 1);
        l += __shfl_xor(l, 2);
        l += __shfl_xor(l, 4);
        l += __shfl_xor(l, 8);
        l += __shfl_xor(l, 16);
        const int r_ = (reg & 3) + 8 * (reg >> 2) + 4 * g;
        float ldv = __shfl(ld, 2 * r_);
        if (col == 0) ssum += ldv + LN2f * __builtin_amdgcn_logf(l);
    }
    ssum += __shfl_xor(ssum, 32);   // combine the two half-wave row groups

    if (lane == 0) red[w] = ssum;
    __syncthreads();
    if (tid == 0) partials[blockIdx.x] = red[0] + red[1] + red[2] + red[3];
}

// Kernel 3: deterministic reduction of per-block partials -> mean.
__global__ void dce_finish(const float* __restrict__ partials,
                           float* __restrict__ out, int nblocks, float invN) {
    int tid = threadIdx.x;  // 256
    float s = 0.f;
    for (int i = tid; i < nblocks; i += 256) s += partials[i];
#pragma unroll
    for (int d = 1; d < 64; d <<= 1) s += __shfl_xor(s, d);
    __shared__ float red[4];
    if ((tid & 63) == 0) red[tid >> 6] = s;
    __syncthreads();
    if (tid == 0) out[0] = (red[0] + red[1] + red[2] + red[3]) * invN;
}

extern "C" void kernel_launch(void* const* d_in, const int* in_sizes, int n_in,
                              void* d_out, int out_size, void* d_ws, size_t ws_size,
                              hipStream_t stream) {
    const float* feats = (const float*)d_in[0];
    const float* protos = (const float*)d_in[1];
    const int* labels = (const int*)d_in[2];
    const int N = in_sizes[2];          // 262144
    const int C = in_sizes[1] / 128;    // 1024
    float* out = (float*)d_out;

    // Workspace: [bpf: C*128*2B][ysqn: C*4B][partials: N/128*4B]
    unsigned short* bpf = (unsigned short*)d_ws;
    float* ysqn = (float*)((char*)d_ws + (size_t)C * 128 * 2);
    float* partials = ysqn + C;
    const int nblocks = N / 128;   // 2048 blocks of 256 threads

    dce_prep<<<C, 64, 0, stream>>>(protos, bpf, ysqn);
    dce_main<<<nblocks, 256, 0, stream>>>(feats, protos, bpf, ysqn, labels, partials, C);
    dce_finish<<<1, 256, 0, stream>>>(partials, out, nblocks, 1.0f / (float)N);
}